// Round 4
// baseline (301.067 us; speedup 1.0000x reference)
//
#include <hip/hip_runtime.h>

#define NN   16
#define CC   3
#define FOUT 64
#define HH   256
#define WW   256
#define KK   3
#define HO   254
#define WO   254

typedef float f32x4 __attribute__((ext_vector_type(4), aligned(16)));

// Compute one output row (4 cols/lane) from 3 input-row slots.
// Window regs per slot: even rows use [A0 A1 A2 A3 B0 B1] (output cols 4l..4l+3),
// odd rows use [A2 A3 B0 B1 B2 B3] (output cols 4l+2..4l+5).
// Lane 63 loads A from col 252, B from col 0, so the SAME code computes its
// edge values: even acc[0:2] = cols 252,253; odd acc[2:4] = cols 0,1.
template <int S0, int S1, int S2, bool ODD>
__device__ __forceinline__ f32x4 crow(const f32x4* A, const f32x4* B,
                                      const float* w, float bv)
{
    float win[3][6];
    const int ss[3] = {S0, S1, S2};
    #pragma unroll
    for (int r = 0; r < 3; ++r) {
        const int s = ss[r];
        if (!ODD) {
            win[r][0] = A[s][0]; win[r][1] = A[s][1]; win[r][2] = A[s][2];
            win[r][3] = A[s][3]; win[r][4] = B[s][0]; win[r][5] = B[s][1];
        } else {
            win[r][0] = A[s][2]; win[r][1] = A[s][3]; win[r][2] = B[s][0];
            win[r][3] = B[s][1]; win[r][4] = B[s][2]; win[r][5] = B[s][3];
        }
    }
    f32x4 acc = {bv, bv, bv, bv};
    #pragma unroll
    for (int dr = 0; dr < 3; ++dr)
        #pragma unroll
        for (int dc = 0; dc < 3; ++dc) {
            const float wq = w[dr * 3 + dc];
            #pragma unroll
            for (int c = 0; c < 4; ++c)
                acc[c] = fmaf(wq, win[dr][dc + c], acc[c]);
        }
    return acc;
}

__global__ __launch_bounds__(256) void conv2dcq_kernel(
    const float* __restrict__ x,       // (N, C, H, W)
    const float* __restrict__ weight,  // (F, C, K, K)
    const float* __restrict__ bias,    // (F,)
    float* __restrict__ out)           // (N, F, HO, WO)
{
    const int tid  = threadIdx.x;
    const int lane = tid & 63;
    const int wave = tid >> 6;

    // Block = one (n,f) output plane; wave = one quarter of its rows.
    // Each wave writes a 64KB SEQUENTIAL stream (vs 1KB bursts 258KB apart
    // before) -> DRAM page locality + same-wave merging of the partial
    // row-boundary cache lines (1016 % 64 = 56).
    // XCD chunk swizzle (bijective: 1024 = 8*128): consecutive (n,f) share an
    // XCD so the channel-0 input planes stay L2-resident per XCD.
    const int bid = (int)blockIdx.x;
    const int swz = (bid & 7) * 128 + (bid >> 3);
    const int n = swz >> 6;
    const int f = swz & 63;

    const int i0   = wave * 64;                 // quarter start row (even)
    const int rows = (wave == 3) ? 62 : 64;

    // Weights + bias are block-uniform -> scalar (SGPR) loads, no LDS.
    const float* wp = weight + f * (CC * KK * KK) + (CC - 1) * (KK * KK);
    float w[9];
    #pragma unroll
    for (int k = 0; k < 9; ++k) w[k] = wp[k];
    const float bv = bias[f];

    // Per-lane input windows (16B-aligned: input rows are 1024B).
    const int colA = (lane < 63) ? 4 * lane     : 252;
    const int colB = (lane < 63) ? 4 * lane + 4 : 0;

    const float* xrow = x + (size_t)n * (CC * HH * WW);
    float* op = out + ((size_t)n * FOUT + f) * (HO * WO) + (size_t)i0 * WO;

    f32x4 A[4], B[4];   // rolling input rows, slot = row & 3

#define LOADROW(s, r) do {                                             \
        A[s] = *(const f32x4*)(xrow + (size_t)(r) * WW + colA);        \
        B[s] = *(const f32x4*)(xrow + (size_t)(r) * WW + colB);        \
    } while (0)

    // Even row store: lanes 0..62 dwordx4 at col 4l (rowbase==0 mod 16, 16B
    // aligned); lane 63 float2 (cols 252,253). Odd row store: lanes 0..62 at
    // col 4l+2 (rowbase==8 mod 16 -> aligned); lane 63 float2 at col 0.
#define STORE_E(acc) do {                                              \
        if (lane < 63) *(f32x4*)(op + colA) = (acc);                   \
        else *(float2*)(op + colA) = make_float2((acc)[0], (acc)[1]);  \
    } while (0)
#define STORE_O(acc) do {                                              \
        if (lane < 63) *(f32x4*)(op + colA + 2) = (acc);               \
        else *(float2*)(op) = make_float2((acc)[2], (acc)[3]);         \
    } while (0)

    LOADROW(0, i0 + 0);
    LOADROW(1, i0 + 1);
    LOADROW(2, i0 + 2);

    int r = i0;
    const int nIter = rows >> 2;
    for (int it = 0; it < nIter; ++it, r += 4) {
        LOADROW(3, r + 3);
        { f32x4 a = crow<0,1,2,false>(A, B, w, bv); STORE_E(a); op += WO; }
        LOADROW(0, r + 4);
        { f32x4 a = crow<1,2,3,true >(A, B, w, bv); STORE_O(a); op += WO; }
        LOADROW(1, r + 5);
        { f32x4 a = crow<2,3,0,false>(A, B, w, bv); STORE_E(a); op += WO; }
        LOADROW(2, r + 6);
        { f32x4 a = crow<3,0,1,true >(A, B, w, bv); STORE_O(a); op += WO; }
    }
    if (rows & 2) {   // wave 3 tail: output rows 252,253 (slots hold 252..254)
        LOADROW(3, r + 3);   // input row 255
        { f32x4 a = crow<0,1,2,false>(A, B, w, bv); STORE_E(a); op += WO; }
        { f32x4 a = crow<1,2,3,true >(A, B, w, bv); STORE_O(a); }
    }

#undef LOADROW
#undef STORE_E
#undef STORE_O
}

extern "C" void kernel_launch(void* const* d_in, const int* in_sizes, int n_in,
                              void* d_out, int out_size, void* d_ws, size_t ws_size,
                              hipStream_t stream) {
    const float* x      = (const float*)d_in[0];
    const float* weight = (const float*)d_in[1];
    const float* bias   = (const float*)d_in[2];
    float* out          = (float*)d_out;

    const int blocks = NN * FOUT;              // 1024 blocks = one (n,f) plane each
    conv2dcq_kernel<<<blocks, 256, 0, stream>>>(x, weight, bias, out);
}